// Round 7
// baseline (643.366 us; speedup 1.0000x reference)
//
#include <hip/hip_runtime.h>
#include <hip/hip_cooperative_groups.h>
#include <hip/hip_bf16.h>
#include <cstdint>

// KAN MLP: 256->512->512->256, B=8192, cubic B-splines (uniform grid h=0.25,
// knots -1.75..1.75, 11 bases), BN at the end.
//
// Round-11: round-6 showed kernel-time sum ~190 us vs 342 us wall -> ~150 us
// of inter-kernel cost (13 dispatch boundaries: launch latency + drain +
// cross-XCD L2 writeback/invalidate of the 50-100 MB A'/P handoffs).
// This round fuses the WHOLE network into ONE cooperative kernel:
//   grid = 256 blocks x 512 threads (the gemm shape, 1 block/CU, 128 KB LDS
//   -> co-residency guaranteed), hipLaunchCooperativeKernel + grid.sync()
//   between 7 phases: [packW x3 + expand0] -> gemm0 -> expand1 -> gemm1 ->
//   expand2 -> gemm2 -> bn.
// Phase bodies are byte-identical to round-6's verified kernels. Expand work
// is remapped bijectively (block bid handles A'-panel p=bid&31, the panel its
// own gemm phase reads -> XCD-L2 affinity for free; same coalescing).
// GEMM (round-6/9 core, unchanged): A' tiled [p][kb][256][32] = contiguous
// 16 KB subtile bursts; 256x256 tile, BK=32; 8 waves 2Mx4N, wave 128x64
// acc[8][4]; conflict-free chunk-XOR swizzle (verified 0 conflicts);
// reg-dbuf frags; 4 LDS slots; stage t+3; counted vmcnt(4); raw s_barrier;
// fp16 split-K partials (L0/L1 SK=4, L2 SK=8).
//
// Workspace (146,800,640 bytes):
//   A'  @ 0          : 8192*6144*2 = 100,663,296 (tiled layout, all layers)
//   W0  @ 100663296  : 3,145,728
//   W1  @ 103809024  : 6,291,456
//   W2  @ 110100480  : 3,145,728
//   P   @ 113246208  : fp16 partials, 33,554,432 (L0/L1: 4 x 8MB; L2: 8 x 4MB)

namespace cg = cooperative_groups;

typedef unsigned short ushort_t;
typedef __bf16 bf16x8 __attribute__((ext_vector_type(8)));
typedef float f32x4 __attribute__((ext_vector_type(4)));
typedef _Float16 f16x4 __attribute__((ext_vector_type(4)));
typedef _Float16 f16x8 __attribute__((ext_vector_type(8)));

#define SLOTE 16384                    // LDS slot elements (32 KB): A 8K + B 8K
#define PS01  ((size_t)8192 * 512)     // L0/L1 partial stride (elems)
#define PS2   ((size_t)8192 * 256)     // L2 partial stride (elems)

__device__ __forceinline__ ushort_t f2bf(float f) {
    __bf16 h = (__bf16)f;  // RNE
    return __builtin_bit_cast(ushort_t, h);
}

// async global->LDS 16B copy; LDS dest must be wave-uniform base + lane*16.
__device__ __forceinline__ void gload_lds16(const void* g, void* lds) {
    __builtin_amdgcn_global_load_lds(
        (const __attribute__((address_space(1))) unsigned int*)(uintptr_t)g,
        (__attribute__((address_space(3))) unsigned int*)(unsigned int)(uintptr_t)lds,
        16, 0, 0);
}

// x -> [gelu, b0..b10] (12 bf16). Direct cardinal cubic B-spline:
// basis_j(x) = b(xs - j), xs=(x+1.75)*4;  b(t), a=|t-2|:
//   a<=1: (4-6a^2+3a^3)/6 ; 1<a<2: (2-a)^3/6 ; else 0.
__device__ __forceinline__ void expand12(float x, ushort_t* o) {
    float x3 = x * x * x;
    float y  = 0.7978845608028654f * (x + 0.044715f * x3);
    float e  = __expf(2.0f * y);
    float th = 1.0f - 2.0f / (e + 1.0f);       // tanh(y)
    o[0] = f2bf(0.5f * x * (1.0f + th));
    float xs = (x + 1.75f) * 4.0f;
#pragma unroll
    for (int j = 0; j < 11; ++j) {
        float t  = xs - (float)j;
        float a  = fabsf(t - 2.0f);
        float p1 = (3.0f * a - 6.0f) * a * a + 4.0f;   // a<=1 branch
        float c  = 2.0f - a;
        float p2 = c * c * c;                          // 1<a<2 branch
        float v  = (a <= 1.0f) ? p1 : fmaxf(p2, 0.0f);
        o[1 + j] = f2bf(v * (1.0f / 6.0f));
    }
}

// pack 32 bf16 (from a statically-offset ushort window) into 4 uint4 chunks
__device__ __forceinline__ void pack32(const ushort_t* s, uint4* o) {
#pragma unroll
    for (int c = 0; c < 4; ++c) {
        o[c].x = (unsigned)s[c * 8 + 0] | ((unsigned)s[c * 8 + 1] << 16);
        o[c].y = (unsigned)s[c * 8 + 2] | ((unsigned)s[c * 8 + 3] << 16);
        o[c].z = (unsigned)s[c * 8 + 4] | ((unsigned)s[c * 8 + 5] << 16);
        o[c].w = (unsigned)s[c * 8 + 6] | ((unsigned)s[c * 8 + 7] << 16);
    }
}

// W[o][i*12+0]=base_w[o][i]; W[o][i*12+1+k]=spline_w[o][i][k].
__device__ __forceinline__ void pack_w_item(
    const float* __restrict__ bw, const float* __restrict__ sw,
    ushort_t* __restrict__ W, int idx)
{
    union { ushort_t us[12]; uint2 v[3]; } pk;
    pk.us[0] = f2bf(bw[idx]);
    const float* s = sw + (size_t)idx * 11;
#pragma unroll
    for (int k = 0; k < 11; ++k) pk.us[1 + k] = f2bf(s[k]);
    uint2* dst = (uint2*)(W + (size_t)idx * 12);
    dst[0] = pk.v[0]; dst[1] = pk.v[1]; dst[2] = pk.v[2];
}

// ---------------------------------------------------------------------------
// Expansion phase (round-6 body, panel-affine remap): block bid handles
// A'-panel p = bid&31 (the one its gemm phase reads), item e = (bid>>5)*512+t.
// row = e&255, cg = e>>8. Reads 32 contiguous inputs of row b (X fp32 or
// sum of 4 fp16 partials); writes the 12 whole 64-B A'-lines (kb=12cg..+11).
// ---------------------------------------------------------------------------
template <int KB, bool FROMX>
__device__ __forceinline__ void expand_phase(
    const float* __restrict__ X, const _Float16* __restrict__ Pp,
    ushort_t* __restrict__ A, int bid, int t)
{
    constexpr int F   = KB * 8 / 3;               // 96->256, 192->512
    constexpr int NCG = F / 32;                   // 8 / 16
    const int p = bid & 31;
    const int e = (bid >> 5) * 512 + t;           // 0..4095
    if (e >= 256 * NCG) return;                   // (helper return only)
    const int row = e & 255;
    const int cg  = e >> 8;
    const int b   = p * 256 + row;

    float h[32];
    if (FROMX) {
        const float4* xr = (const float4*)(X + (size_t)b * F + cg * 32);
#pragma unroll
        for (int v = 0; v < 8; ++v) {
            float4 f = xr[v];
            h[4 * v + 0] = f.x; h[4 * v + 1] = f.y;
            h[4 * v + 2] = f.z; h[4 * v + 3] = f.w;
        }
    } else {
#pragma unroll
        for (int u = 0; u < 32; ++u) h[u] = 0.f;
#pragma unroll
        for (int z = 0; z < 4; ++z) {
            const f16x8* pr = (const f16x8*)(Pp + z * PS01 + (size_t)b * F + cg * 32);
#pragma unroll
            for (int v = 0; v < 4; ++v) {
                f16x8 a = pr[v];
#pragma unroll
                for (int ee = 0; ee < 8; ++ee) h[8 * v + ee] += (float)a[ee];
            }
        }
    }

    const size_t lbase = ((size_t)p * KB + 12 * cg) * 256 + row;
#pragma unroll
    for (int ci8 = 0; ci8 < 4; ++ci8) {
        ushort_t us[96];
#pragma unroll
        for (int u = 0; u < 8; ++u) expand12(h[ci8 * 8 + u], us + 12 * u);
#pragma unroll
        for (int kk = 0; kk < 3; ++kk) {
            uint4 o[4];
            pack32(us + 32 * kk, o);
            uint4* dst = (uint4*)(A + (lbase + (size_t)(3 * ci8 + kk) * 256) * 32);
            dst[0] = o[0]; dst[1] = o[1]; dst[2] = o[2]; dst[3] = o[3];
        }
    }
}

// ---------------------------------------------------------------------------
// GEMM phase (round-6 body verbatim; blockIdx -> bx/by/bz params).
// C_z[M,N] = A'[M,kslice] @ W[N,kslice]^T (bf16 in, fp16 out).
// ---------------------------------------------------------------------------
__device__ void gemm_phase(
    const ushort_t* __restrict__ A,  // tiled [p][KBT][256][32]
    const ushort_t* __restrict__ W,  // N x K row-major
    _Float16* __restrict__ C,        // split-K partials (fp16), z*M*N apart
    int M, int N, int KBT, int scps, // scps even, >= 4
    int bx, int by, int bz, int t)
{
    extern __shared__ __align__(16) ushort_t lds[];   // 4*SLOTE = 128 KB

    const int l   = t & 63;
    const int w   = t >> 6;        // 0..7
    const int wm  = w >> 2;        // 0..1  (M half)
    const int wn  = w & 3;         // 0..3  (N quarter)
    const int l15 = l & 15;
    const int q   = l >> 4;        // 0..3
    const int K   = KBT << 5;
    const int blockN = by * 256;
    const int kb0 = bz * scps;
    const int nt  = scps;
    _Float16* Cz = C + (size_t)bz * M * N;

    const ushort_t* Apan = A + (size_t)bx * KBT * 8192;
    const ushort_t* Wb   = W + (size_t)blockN * K;

    // stage one 32-k subtile: A = contiguous 16 KB (tiled layout); B = 256
    // rows x 64 B strided. Source chunk XOR'd within each 64-B line so LDS
    // (row,c) holds logical chunk c ^ ((row>>1)&3); dest linear (required).
    auto stage = [&](int kb, int slot) {
        ushort_t* da = lds + slot * SLOTE;
        ushort_t* db = da + 8192;
        const ushort_t* sa = Apan + (size_t)kb * 8192;
#pragma unroll
        for (int it = 0; it < 2; ++it) {
            int s = it * 512 + t;
            int row = s >> 2, g = (s & 3) ^ ((row >> 1) & 3);
            gload_lds16(sa + (row << 5) + (g << 3), da + s * 8);
        }
#pragma unroll
        for (int it = 0; it < 2; ++it) {
            int s = it * 512 + t;
            int row = s >> 2, g = (s & 3) ^ ((row >> 1) & 3);
            gload_lds16(Wb + ((size_t)row * K + (kb << 5) + (g << 3)), db + s * 8);
        }
    };

    // 12 ds_read_b128 of one subtile's fragments into the given reg arrays.
    auto ldfrags = [&](int slot, bf16x8* afr, bf16x8* bfr) {
        const ushort_t* Ac = lds + slot * SLOTE;
        const ushort_t* Bc = Ac + 8192;
#pragma unroll
        for (int ni = 0; ni < 4; ++ni) {
            int n = wn * 64 + ni * 16 + l15;
            bfr[ni] = *(const bf16x8*)&Bc[(size_t)((n << 2) + (q ^ ((n >> 1) & 3))) * 8];
        }
#pragma unroll
        for (int mi = 0; mi < 8; ++mi) {
            int m = wm * 128 + mi * 16 + l15;
            afr[mi] = *(const bf16x8*)&Ac[(size_t)((m << 2) + (q ^ ((m >> 1) & 3))) * 8];
        }
    };

    f32x4 acc[8][4];
#pragma unroll
    for (int i = 0; i < 8; ++i)
#pragma unroll
        for (int j = 0; j < 4; ++j) acc[i][j] = (f32x4){0.f, 0.f, 0.f, 0.f};

    // prologue: stage 0,1,2; ensure 0 AND 1 resident (frags(1) read at tt=0).
    stage(kb0 + 0, 0); stage(kb0 + 1, 1); stage(kb0 + 2, 2);
    asm volatile("s_waitcnt vmcnt(4)" ::: "memory");
    __builtin_amdgcn_s_barrier();

    bf16x8 aA[8], bA[4], aB[8], bB[4];
    ldfrags(0, aA, bA);
    asm volatile("s_waitcnt lgkmcnt(0)" ::: "memory");

    // per-subtile body: compute on (ac,bc)=frags(tt); prefetch frags(tt+1)
    // into (an,bn); stage subtile tt+3.
    auto body = [&](int tt, bf16x8* ac, bf16x8* bc, bf16x8* an, bf16x8* bn) {
        if (tt + 3 < nt) stage(kb0 + tt + 3, (tt + 3) & 3);
        if (tt + 1 < nt) ldfrags((tt + 1) & 3, an, bn);
        __builtin_amdgcn_sched_barrier(0);   // pin loads/reads before MFMAs
        __builtin_amdgcn_s_setprio(1);
#pragma unroll
        for (int mi = 0; mi < 8; ++mi)
#pragma unroll
            for (int ni = 0; ni < 4; ++ni)
                acc[mi][ni] = __builtin_amdgcn_mfma_f32_16x16x32_bf16(
                    ac[mi], bc[ni], acc[mi][ni], 0, 0, 0);
        __builtin_amdgcn_s_setprio(0);
        // alt-frag reads drained under the MFMA shadow -> near-free wait.
        asm volatile("s_waitcnt lgkmcnt(0)" ::: "memory");
        // subtile tt+2 resident for next iter's prefetch; tt+3 in flight.
        if (tt + 3 < nt)      asm volatile("s_waitcnt vmcnt(4)" ::: "memory");
        else if (tt + 2 < nt) asm volatile("s_waitcnt vmcnt(0)" ::: "memory");
        __builtin_amdgcn_s_barrier();
    };

    for (int tt = 0; tt < nt; tt += 2) {
        body(tt,     aA, bA, aB, bB);
        body(tt + 1, aB, bB, aA, bA);
    }

    const int blockM = bx * 256;
    // epilogue: fp16 stores into this split's partial buffer
#pragma unroll
    for (int ni = 0; ni < 4; ++ni) {
        int n = blockN + wn * 64 + ni * 16 + l15;
#pragma unroll
        for (int mi = 0; mi < 8; ++mi) {
            int mb = blockM + wm * 128 + mi * 16 + q * 4;
#pragma unroll
            for (int r = 0; r < 4; ++r)
                Cz[(size_t)(mb + r) * N + n] = (_Float16)acc[mi][ni][r];
        }
    }
}

// ---------------------------------------------------------------------------
// BN phase: out = gamma*rsqrt(var+eps)*(sum of 8 fp16 partials - mean) + beta.
// 524288 float4 items = 4 per thread.
// ---------------------------------------------------------------------------
__device__ __forceinline__ void bn_phase(
    const _Float16* __restrict__ Q,
    const float* __restrict__ gamma, const float* __restrict__ beta,
    const float* __restrict__ mean,  const float* __restrict__ var,
    float4* __restrict__ out, int tid)
{
#pragma unroll
    for (int k = 0; k < 4; ++k) {
        int i = tid + k * 131072;
        float sx = 0.f, sy = 0.f, sz = 0.f, sw = 0.f;
#pragma unroll
        for (int s = 0; s < 8; ++s) {
            f16x4 v = *(const f16x4*)(Q + s * PS2 + 4 * (size_t)i);
            sx += (float)v.x; sy += (float)v.y; sz += (float)v.z; sw += (float)v.w;
        }
        int nb = (i * 4) & 255;
        float4 g  = *(const float4*)(gamma + nb);
        float4 be = *(const float4*)(beta + nb);
        float4 mn = *(const float4*)(mean + nb);
        float4 vr = *(const float4*)(var + nb);
        float4 o;
        o.x = g.x * rsqrtf(vr.x + 1e-5f) * (sx - mn.x) + be.x;
        o.y = g.y * rsqrtf(vr.y + 1e-5f) * (sy - mn.y) + be.y;
        o.z = g.z * rsqrtf(vr.z + 1e-5f) * (sz - mn.z) + be.z;
        o.w = g.w * rsqrtf(vr.w + 1e-5f) * (sw - mn.w) + be.w;
        out[i] = o;
    }
}

// ---------------------------------------------------------------------------
struct KArgs {
    const float* x;
    const float* bw0; const float* sw0;
    const float* bw1; const float* sw1;
    const float* bw2; const float* sw2;
    const float* gamma; const float* beta;
    const float* mean;  const float* var;
    ushort_t* A; ushort_t* W0; ushort_t* W1; ushort_t* W2;
    _Float16* P; float* out;
};

__global__ __launch_bounds__(512, 2) void fused_kernel(KArgs a)
{
    const int bid = blockIdx.x;
    const int t   = threadIdx.x;
    const int tid = bid * 512 + t;
    cg::grid_group grid = cg::this_grid();

    // phase 0: weight packs (W0:1, W1:2, W2:1 items/thread) + expand L0
    pack_w_item(a.bw0, a.sw0, a.W0, tid);
    pack_w_item(a.bw1, a.sw1, a.W1, tid);
    pack_w_item(a.bw1, a.sw1, a.W1, tid + 131072);
    pack_w_item(a.bw2, a.sw2, a.W2, tid);
    expand_phase<96, true>(a.x, nullptr, a.A, bid, t);
    grid.sync();

    // layer 0 GEMM: K=3072 (KBT=96), N=512, SK=4, grid (32,2,4)
    gemm_phase(a.A, a.W0, a.P, 8192, 512, 96, 24, bid & 31, (bid >> 5) & 1, bid >> 6, t);
    grid.sync();

    // expand L1: sum 4 partials, K=6144 (KB=192)
    expand_phase<192, false>(nullptr, a.P, a.A, bid, t);
    grid.sync();

    // layer 1 GEMM: K=6144 (KBT=192), N=512, SK=4, grid (32,2,4)
    gemm_phase(a.A, a.W1, a.P, 8192, 512, 192, 48, bid & 31, (bid >> 5) & 1, bid >> 6, t);
    grid.sync();

    // expand L2: sum 4 partials
    expand_phase<192, false>(nullptr, a.P, a.A, bid, t);
    grid.sync();

    // layer 2 GEMM: K=6144 (KBT=192), N=256, SK=8, grid (32,1,8)
    gemm_phase(a.A, a.W2, a.P, 8192, 256, 192, 24, bid & 31, 0, bid >> 5, t);
    grid.sync();

    // BN + 8-way split-K reduce
    bn_phase(a.P, a.gamma, a.beta, a.mean, a.var, (float4*)a.out, tid);
}

// ---------------------------------------------------------------------------
extern "C" void kernel_launch(void* const* d_in, const int* in_sizes, int n_in,
                              void* d_out, int out_size, void* d_ws, size_t ws_size,
                              hipStream_t stream) {
    char* ws = (char*)d_ws;
    KArgs args;
    args.x     = (const float*)d_in[0];
    args.bw0   = (const float*)d_in[2];
    args.sw0   = (const float*)d_in[3];
    args.bw1   = (const float*)d_in[5];
    args.sw1   = (const float*)d_in[6];
    args.bw2   = (const float*)d_in[8];
    args.sw2   = (const float*)d_in[9];
    args.gamma = (const float*)d_in[10];
    args.beta  = (const float*)d_in[11];
    args.mean  = (const float*)d_in[12];
    args.var   = (const float*)d_in[13];
    args.A     = (ushort_t*)(ws);
    args.W0    = (ushort_t*)(ws + 100663296);
    args.W1    = (ushort_t*)(ws + 103809024);
    args.W2    = (ushort_t*)(ws + 110100480);
    args.P     = (_Float16*)(ws + 113246208);
    args.out   = (float*)d_out;

    void* params[] = { (void*)&args };
    hipLaunchCooperativeKernel((const void*)fused_kernel, dim3(256), dim3(512),
                               params, 131072u, stream);
}

// Round 8
// 389.206 us; speedup vs baseline: 1.6530x; 1.6530x over previous
//
#include <hip/hip_runtime.h>
#include <hip/hip_bf16.h>
#include <cstdint>

// KAN MLP: 256->512->512->256, B=8192, cubic B-splines (uniform grid h=0.25,
// knots -1.75..1.75, 11 bases), BN at the end.
//
// Round-12: round-7's cooperative fusion REGRESSED (643 us): memory-bound
// phases lost occupancy (24%), WRITE_SIZE 620 MB. Reverted to split kernels.
// Round-6 ledger balanced: subtile period 2950 cyc = MFMA 1242 + LDS 1400
// (96 ds_read_b128 + 32 KB staging writes) running SERIALLY -- every prior
// schedule kept A AND B in LDS. This round: A LEAVES LDS.
//   - A' tiled [p][kb][256][32] makes the wave's A-fragment a perfectly
//     coalesced DIRECT global load: af[mi] = 16 B/lane, lanes (l15,q) span
//     1 KB contiguous. No staging, no swizzle, straight to the reg-dbuf
//     arrays that already existed.
//   - LDS now B-only: 4 slots x 16 KB = 64 KB; DS/subtile drops ~2650 ->
//     ~500 cyc (32 ds_read_b128 + 16 KB writes), under the MFMA shadow.
//   - vmcnt pipeline: per body issue {ldfrags_B(t+1), Aload(t+1)[8],
//     stageB(t+3)[2]}; trailing lgkmcnt(0) + vmcnt(2) (A(t+1)+B(t+2) done,
//     B(t+3) in flight); raw s_barrier. Same traffic, same addresses as
//     round-6 -- only the destination (VGPR vs LDS) changes.
//   - prep_kernel merges 3 weight-packs + expand-L0 (block-uniform ranges):
//     10 dispatches -> 7 (~30 us of boundary cost).
// Expand L1/L2, bn, fp16 split-K partials: round-6 verbatim.
// Grids: L0 (32,2,4), L1 (32,2,4), L2 (32,1,8) = 256 blocks = 1 block/CU.
//
// Workspace (146,800,640 bytes):
//   A'  @ 0          : 8192*6144*2 = 100,663,296 (tiled layout, all layers)
//   W0  @ 100663296  : 3,145,728
//   W1  @ 103809024  : 6,291,456
//   W2  @ 110100480  : 3,145,728
//   P   @ 113246208  : fp16 partials, 33,554,432 (L0/L1: 4 x 8MB; L2: 8 x 4MB)

typedef unsigned short ushort_t;
typedef __bf16 bf16x8 __attribute__((ext_vector_type(8)));
typedef float f32x4 __attribute__((ext_vector_type(4)));
typedef _Float16 f16x4 __attribute__((ext_vector_type(4)));
typedef _Float16 f16x8 __attribute__((ext_vector_type(8)));

#define PS01  ((size_t)8192 * 512)     // L0/L1 partial stride (elems)
#define PS2   ((size_t)8192 * 256)     // L2 partial stride (elems)

__device__ __forceinline__ ushort_t f2bf(float f) {
    __bf16 h = (__bf16)f;  // RNE
    return __builtin_bit_cast(ushort_t, h);
}

// async global->LDS 16B copy; LDS dest must be wave-uniform base + lane*16.
__device__ __forceinline__ void gload_lds16(const void* g, void* lds) {
    __builtin_amdgcn_global_load_lds(
        (const __attribute__((address_space(1))) unsigned int*)(uintptr_t)g,
        (__attribute__((address_space(3))) unsigned int*)(unsigned int)(uintptr_t)lds,
        16, 0, 0);
}

// x -> [gelu, b0..b10] (12 bf16). Direct cardinal cubic B-spline:
// basis_j(x) = b(xs - j), xs=(x+1.75)*4;  b(t), a=|t-2|:
//   a<=1: (4-6a^2+3a^3)/6 ; 1<a<2: (2-a)^3/6 ; else 0.
__device__ __forceinline__ void expand12(float x, ushort_t* o) {
    float x3 = x * x * x;
    float y  = 0.7978845608028654f * (x + 0.044715f * x3);
    float e  = __expf(2.0f * y);
    float th = 1.0f - 2.0f / (e + 1.0f);       // tanh(y)
    o[0] = f2bf(0.5f * x * (1.0f + th));
    float xs = (x + 1.75f) * 4.0f;
#pragma unroll
    for (int j = 0; j < 11; ++j) {
        float t  = xs - (float)j;
        float a  = fabsf(t - 2.0f);
        float p1 = (3.0f * a - 6.0f) * a * a + 4.0f;   // a<=1 branch
        float c  = 2.0f - a;
        float p2 = c * c * c;                          // 1<a<2 branch
        float v  = (a <= 1.0f) ? p1 : fmaxf(p2, 0.0f);
        o[1 + j] = f2bf(v * (1.0f / 6.0f));
    }
}

// pack 32 bf16 (from a statically-offset ushort window) into 4 uint4 chunks
__device__ __forceinline__ void pack32(const ushort_t* s, uint4* o) {
#pragma unroll
    for (int c = 0; c < 4; ++c) {
        o[c].x = (unsigned)s[c * 8 + 0] | ((unsigned)s[c * 8 + 1] << 16);
        o[c].y = (unsigned)s[c * 8 + 2] | ((unsigned)s[c * 8 + 3] << 16);
        o[c].z = (unsigned)s[c * 8 + 4] | ((unsigned)s[c * 8 + 5] << 16);
        o[c].w = (unsigned)s[c * 8 + 6] | ((unsigned)s[c * 8 + 7] << 16);
    }
}

// W[o][i*12+0]=base_w[o][i]; W[o][i*12+1+k]=spline_w[o][i][k].
__device__ __forceinline__ void pack_w_item(
    const float* __restrict__ bw, const float* __restrict__ sw,
    ushort_t* __restrict__ W, int idx)
{
    union { ushort_t us[12]; uint2 v[3]; } pk;
    pk.us[0] = f2bf(bw[idx]);
    const float* s = sw + (size_t)idx * 11;
#pragma unroll
    for (int k = 0; k < 11; ++k) pk.us[1 + k] = f2bf(s[k]);
    uint2* dst = (uint2*)(W + (size_t)idx * 12);
    dst[0] = pk.v[0]; dst[1] = pk.v[1]; dst[2] = pk.v[2];
}

// ---------------------------------------------------------------------------
// Tiled expansion body (round-6 verbatim): item = (b, cg), idx = cg*8192 + b.
// Reads input cols [32cg, 32cg+32) of row b contiguously (X fp32 or sum of
// 4 fp16 partials), writes the 12 whole 64-B A'-lines (kb = 12cg..12cg+11).
// Lanes = consecutive b -> coalesced 4-KB wave spans.
// ---------------------------------------------------------------------------
template <int KB, bool FROMX>
__device__ __forceinline__ void expand_item(
    const float* __restrict__ X, const _Float16* __restrict__ Pp,
    ushort_t* __restrict__ A, int idx)
{
    constexpr int F = KB * 8 / 3;                 // 96->256, 192->512
    const int b   = idx & 8191;
    const int cg  = idx >> 13;                    // 0..F/32-1
    const int row = b & 255;
    const int p   = b >> 8;

    float h[32];
    if (FROMX) {
        const float4* xr = (const float4*)(X + (size_t)b * F + cg * 32);
#pragma unroll
        for (int v = 0; v < 8; ++v) {
            float4 f = xr[v];
            h[4 * v + 0] = f.x; h[4 * v + 1] = f.y;
            h[4 * v + 2] = f.z; h[4 * v + 3] = f.w;
        }
    } else {
#pragma unroll
        for (int u = 0; u < 32; ++u) h[u] = 0.f;
#pragma unroll
        for (int z = 0; z < 4; ++z) {
            const f16x8* pr = (const f16x8*)(Pp + z * PS01 + (size_t)b * F + cg * 32);
#pragma unroll
            for (int v = 0; v < 4; ++v) {
                f16x8 a = pr[v];
#pragma unroll
                for (int e = 0; e < 8; ++e) h[8 * v + e] += (float)a[e];
            }
        }
    }

    const size_t lbase = ((size_t)p * KB + 12 * cg) * 256 + row;
#pragma unroll
    for (int ci8 = 0; ci8 < 4; ++ci8) {
        ushort_t us[96];
#pragma unroll
        for (int u = 0; u < 8; ++u) expand12(h[ci8 * 8 + u], us + 12 * u);
#pragma unroll
        for (int kk = 0; kk < 3; ++kk) {
            uint4 o[4];
            pack32(us + 32 * kk, o);
            uint4* dst = (uint4*)(A + (lbase + (size_t)(3 * ci8 + kk) * 256) * 32);
            dst[0] = o[0]; dst[1] = o[1]; dst[2] = o[2]; dst[3] = o[3];
        }
    }
}

// ---------------------------------------------------------------------------
// prep: blocks [0,512) pack W0, [512,1536) W1, [1536,2048) W2 (all block-
// uniform ranges), [2048,2304) expand L0. Replaces 4 dispatches with 1.
// ---------------------------------------------------------------------------
__global__ __launch_bounds__(256) void prep_kernel(
    const float* __restrict__ x,
    const float* __restrict__ bw0, const float* __restrict__ sw0,
    const float* __restrict__ bw1, const float* __restrict__ sw1,
    const float* __restrict__ bw2, const float* __restrict__ sw2,
    ushort_t* __restrict__ W0, ushort_t* __restrict__ W1,
    ushort_t* __restrict__ W2, ushort_t* __restrict__ A)
{
    const int bid = blockIdx.x;
    const int idx = bid * 256 + threadIdx.x;
    if (bid < 512)       pack_w_item(bw0, sw0, W0, idx);
    else if (bid < 1536) pack_w_item(bw1, sw1, W1, idx - 131072);
    else if (bid < 2048) pack_w_item(bw2, sw2, W2, idx - 393216);
    else expand_item<96, true>(x, nullptr, A, idx - 524288);
}

// L1/L2 expand: sum 4 fp16 partials, write A' tiled. 512 blocks x 256.
__global__ __launch_bounds__(256) void expand_kernel(
    const _Float16* __restrict__ P, ushort_t* __restrict__ A)
{
    expand_item<192, false>(nullptr, P, A, blockIdx.x * 256 + threadIdx.x);
}

// ---------------------------------------------------------------------------
// GEMM: C_z[M,N] = A'[M,kslice] @ W[N,kslice]^T (bf16 in, fp16 out).
// A' tiled [p][kb][256][32]; A-fragments loaded DIRECT global->VGPR:
//   af[mi] = A'[kb][wm*128+mi*16+l15][q*8..+7] -- lanes (l15,q) of one load
//   span 1 KB contiguous; 8 loads/wave/subtile, no LDS, no swizzle.
// B via LDS: 4 slots x 16 KB, chunk-XOR swizzle (verified 0 conflicts),
// staged t+3 ahead with gload_lds16.
// Pipeline per subtile t (on frags t in cur regs):
//   {ldfrags_B(t+1)->alt [4 ds_read], Aload(t+1)->alt [8 vmem],
//    stageB(t+3) [2 vmem-lds]} ; sched_barrier ; setprio(1) 32 MFMA ;
//   lgkmcnt(0) ; vmcnt(2)  [A(t+1)+B(t+2) done, B(t+3) in flight] ; barrier.
// Wave tile 128x64 acc[8][4]; 8 waves (wm=w>>2, wn=w&3); split-K over z.
//   A frag: lane holds A[m=l15][k=q*8+j];  C/D: D[m=q*4+r][n=l15].
// ---------------------------------------------------------------------------
__global__ __launch_bounds__(512, 2) void gemm_kernel(
    const ushort_t* __restrict__ A,  // tiled [p][KBT][256][32]
    const ushort_t* __restrict__ W,  // N x K row-major
    _Float16* __restrict__ C,        // split-K partials (fp16), z*M*N apart
    int M, int N, int KBT, int scps) // scps even, >= 4
{
    extern __shared__ __align__(16) ushort_t lds[];   // 4 x 8192 elems = 64 KB

    const int t   = threadIdx.x;
    const int l   = t & 63;
    const int w   = t >> 6;        // 0..7
    const int wm  = w >> 2;        // 0..1  (M half)
    const int wn  = w & 3;         // 0..3  (N quarter)
    const int l15 = l & 15;
    const int q   = l >> 4;        // 0..3
    const int K   = KBT << 5;
    const int blockN = blockIdx.y * 256;
    const int kb0 = blockIdx.z * scps;
    const int nt  = scps;
    _Float16* Cz = C + (size_t)blockIdx.z * M * N;

    const ushort_t* Apan = A + (size_t)blockIdx.x * KBT * 8192;
    const ushort_t* Wb   = W + (size_t)blockN * K;
    // per-lane A offset (elems): row m = wm*128 + l15 (+16*mi), chunk q
    const int aoff = ((wm * 128 + l15) << 5) + (q << 3);

    auto stage_b = [&](int kb, int slot) {
        ushort_t* db = lds + slot * 8192;
#pragma unroll
        for (int it = 0; it < 2; ++it) {
            int s = it * 512 + t;
            int row = s >> 2, g = (s & 3) ^ ((row >> 1) & 3);
            gload_lds16(Wb + ((size_t)row * K + (kb << 5) + (g << 3)), db + s * 8);
        }
    };
    auto ldfrags_b = [&](int slot, bf16x8* bfr) {
        const ushort_t* Bc = lds + slot * 8192;
#pragma unroll
        for (int ni = 0; ni < 4; ++ni) {
            int n = wn * 64 + ni * 16 + l15;
            bfr[ni] = *(const bf16x8*)&Bc[(size_t)((n << 2) + (q ^ ((n >> 1) & 3))) * 8];
        }
    };
    auto load_a = [&](int kb, bf16x8* afr) {
        const ushort_t* sa = Apan + (size_t)kb * 8192 + aoff;
#pragma unroll
        for (int mi = 0; mi < 8; ++mi)
            afr[mi] = *(const bf16x8*)(sa + mi * 512);
    };

    f32x4 acc[8][4];
#pragma unroll
    for (int i = 0; i < 8; ++i)
#pragma unroll
        for (int j = 0; j < 4; ++j) acc[i][j] = (f32x4){0.f, 0.f, 0.f, 0.f};

    bf16x8 aA[8], bA[4], aB[8], bB[4];

    // prologue: A(0) then B(0),B(1),B(2); vmcnt(2) completes A0+B0+B1,
    // leaves B2 in flight (matches steady-state entry {B(tt+2)}).
    load_a(kb0, aA);
    stage_b(kb0 + 0, 0); stage_b(kb0 + 1, 1); stage_b(kb0 + 2, 2);
    asm volatile("s_waitcnt vmcnt(2)" ::: "memory");
    __builtin_amdgcn_s_barrier();
    ldfrags_b(0, bA);
    asm volatile("s_waitcnt lgkmcnt(0)" ::: "memory");

    // body(tt): MFMA on cur (tt); prefetch frags(tt+1) into alt; stage B(tt+3).
    auto body = [&](int tt, bf16x8* ac, bf16x8* bc, bf16x8* an, bf16x8* bn) {
        if (tt + 1 < nt) { ldfrags_b((tt + 1) & 3, bn); load_a(kb0 + tt + 1, an); }
        if (tt + 3 < nt) stage_b(kb0 + tt + 3, (tt + 3) & 3);
        __builtin_amdgcn_sched_barrier(0);   // pin loads/reads before MFMAs
        __builtin_amdgcn_s_setprio(1);
#pragma unroll
        for (int mi = 0; mi < 8; ++mi)
#pragma unroll
            for (int ni = 0; ni < 4; ++ni)
                acc[mi][ni] = __builtin_amdgcn_mfma_f32_16x16x32_bf16(
                    ac[mi], bc[ni], acc[mi][ni], 0, 0, 0);
        __builtin_amdgcn_s_setprio(0);
        // alt frags drained under the MFMA shadow -> near-free waits.
        asm volatile("s_waitcnt lgkmcnt(0)" ::: "memory");
        if (tt + 3 < nt) asm volatile("s_waitcnt vmcnt(2)" ::: "memory");
        else             asm volatile("s_waitcnt vmcnt(0)" ::: "memory");
        __builtin_amdgcn_s_barrier();
    };

    for (int tt = 0; tt < nt; tt += 2) {
        body(tt,     aA, bA, aB, bB);
        body(tt + 1, aB, bB, aA, bA);
    }

    const int blockM = blockIdx.x * 256;
    // epilogue: fp16 stores into this split's partial buffer
#pragma unroll
    for (int ni = 0; ni < 4; ++ni) {
        int n = blockN + wn * 64 + ni * 16 + l15;
#pragma unroll
        for (int mi = 0; mi < 8; ++mi) {
            int mb = blockM + wm * 128 + mi * 16 + q * 4;
#pragma unroll
            for (int r = 0; r < 4; ++r)
                Cz[(size_t)(mb + r) * N + n] = (_Float16)acc[mi][ni][r];
        }
    }
}

// ---------------------------------------------------------------------------
// Final: out = gamma*rsqrt(var+eps)*(sum of 8 fp16 partials - mean) + beta.
// ---------------------------------------------------------------------------
__global__ __launch_bounds__(256) void bn_reduce_kernel(
    const _Float16* __restrict__ Q,
    const float* __restrict__ gamma, const float* __restrict__ beta,
    const float* __restrict__ mean,  const float* __restrict__ var,
    float4* __restrict__ out, int n4)
{
    int i = blockIdx.x * 256 + threadIdx.x;
    if (i >= n4) return;
    float sx = 0.f, sy = 0.f, sz = 0.f, sw = 0.f;
#pragma unroll
    for (int s = 0; s < 8; ++s) {
        f16x4 v = *(const f16x4*)(Q + s * PS2 + 4 * (size_t)i);
        sx += (float)v.x; sy += (float)v.y; sz += (float)v.z; sw += (float)v.w;
    }
    int nb = (i * 4) & 255;
    float4 g  = *(const float4*)(gamma + nb);
    float4 be = *(const float4*)(beta + nb);
    float4 mn = *(const float4*)(mean + nb);
    float4 vr = *(const float4*)(var + nb);
    float4 o;
    o.x = g.x * rsqrtf(vr.x + 1e-5f) * (sx - mn.x) + be.x;
    o.y = g.y * rsqrtf(vr.y + 1e-5f) * (sy - mn.y) + be.y;
    o.z = g.z * rsqrtf(vr.z + 1e-5f) * (sz - mn.z) + be.z;
    o.w = g.w * rsqrtf(vr.w + 1e-5f) * (sw - mn.w) + be.w;
    out[i] = o;
}

// ---------------------------------------------------------------------------
extern "C" void kernel_launch(void* const* d_in, const int* in_sizes, int n_in,
                              void* d_out, int out_size, void* d_ws, size_t ws_size,
                              hipStream_t stream) {
    const float* x     = (const float*)d_in[0];
    const float* bw0   = (const float*)d_in[2];
    const float* sw0   = (const float*)d_in[3];
    const float* bw1   = (const float*)d_in[5];
    const float* sw1   = (const float*)d_in[6];
    const float* bw2   = (const float*)d_in[8];
    const float* sw2   = (const float*)d_in[9];
    const float* gamma = (const float*)d_in[10];
    const float* beta  = (const float*)d_in[11];
    const float* mean  = (const float*)d_in[12];
    const float* var   = (const float*)d_in[13];

    char* ws = (char*)d_ws;
    ushort_t*  Abuf = (ushort_t*)(ws);
    ushort_t*  W0   = (ushort_t*)(ws + 100663296);
    ushort_t*  W1   = (ushort_t*)(ws + 103809024);
    ushort_t*  W2   = (ushort_t*)(ws + 110100480);
    _Float16*  P    = (_Float16*)(ws + 113246208);   // 32 MB fp16 partials
    float*     out  = (float*)d_out;

    const size_t GEMM_LDS = 65536;   // 4 B-slots x 16 KB

    // prep: 3 weight packs + expand L0 in one dispatch
    prep_kernel<<<2304, 256, 0, stream>>>(x, bw0, sw0, bw1, sw1, bw2, sw2,
                                          W0, W1, W2, Abuf);
    // layer 0: K=3072 (KBT=96), N=512, SK=4 (scps=24)
    {
        dim3 g(32, 2, 4);
        gemm_kernel<<<g, 512, GEMM_LDS, stream>>>(Abuf, W0, P, 8192, 512, 96, 24);
    }
    // layer 1: K=6144 (KBT=192), N=512, SK=4 (scps=48)
    expand_kernel<<<512, 256, 0, stream>>>(P, Abuf);
    {
        dim3 g(32, 2, 4);
        gemm_kernel<<<g, 512, GEMM_LDS, stream>>>(Abuf, W1, P, 8192, 512, 192, 48);
    }
    // layer 2: K=6144 (KBT=192), N=256, SK=8 (scps=24)
    expand_kernel<<<512, 256, 0, stream>>>(P, Abuf);
    {
        dim3 g(32, 1, 8);
        gemm_kernel<<<g, 512, GEMM_LDS, stream>>>(Abuf, W2, P, 8192, 256, 192, 24);
    }
    // BN + 8-way split-K reduce -> out
    bn_reduce_kernel<<<2048, 256, 0, stream>>>(
        P, gamma, beta, mean, var, (float4*)out, 8192 * 256 / 4);
}

// Round 9
// 351.877 us; speedup vs baseline: 1.8284x; 1.1061x over previous
//
#include <hip/hip_runtime.h>
#include <hip/hip_bf16.h>
#include <cstdint>

// KAN MLP: 256->512->512->256, B=8192, cubic B-splines (uniform grid h=0.25,
// knots -1.75..1.75, 11 bases), BN at the end.
//
// Round-13: round-8's A-direct regressed (82 us, 24% Mfma): 4x A-traffic
// from L2 (each wn-wave re-loads the same A-half) + unhidden VMEM latency.
// Reverted to LDS-A. Round-6 core = 873 TF = exactly the documented
// 2-barrier-structure ceiling (m97). This round: faithful port of the m201
// 8-phase schedule (the documented 1.7x lever), which none of my three
// earlier pipelining attempts actually matched:
//   - BK=64 K-tiles, 4 phases each, 16 MFMA per phase on a 128x64 wave tile
//   - TWO raw s_barriers per phase ({reads+stage; bar; lgkm0; MFMA; bar})
//   - 2 gload_lds16 staged EVERY phase (one 16-KB half-tile):
//     ph0: Ak0(t+1), ph1: Ak1, ph2: Bk0, ph3: Bk1
//   - counted vmcnt ONLY at dependency points: ph1-end vmcnt(4) (forces
//     Bk1(t) resident for ph2), ph3-end vmcnt(2) (forces Ak0/Ak1/Bk0(t+1)
//     resident for next ph0/ph1; Bk1(t+1) stays in flight). Never 0 mid-loop.
//   - double-buffered LDS 2 x {Ak0|Ak1|Bk0|Bk1} x 16 KB = 128 KB
// Data layout, swizzle, fragment reads, epilogue: round-6 verbatim (A'
// tiled [p][kb32][256][32] -> Ak half-stages are contiguous 16 KB bursts;
// chunk-XOR swizzle measured 0 bank conflicts).
// prep merge kept from round-8 (3 packs + expand0 in one dispatch; 7 total).
// Grids: L0 (32,2,4) tps=12, L1 (32,2,4) tps=24, L2 (32,1,8) tps=12
// = 256 blocks = 1 block/CU.
//
// Workspace (146,800,640 bytes):
//   A'  @ 0          : 8192*6144*2 = 100,663,296 (tiled layout, all layers)
//   W0  @ 100663296  : 3,145,728
//   W1  @ 103809024  : 6,291,456
//   W2  @ 110100480  : 3,145,728
//   P   @ 113246208  : fp16 partials, 33,554,432 (L0/L1: 4 x 8MB; L2: 8 x 4MB)

typedef unsigned short ushort_t;
typedef __bf16 bf16x8 __attribute__((ext_vector_type(8)));
typedef float f32x4 __attribute__((ext_vector_type(4)));
typedef _Float16 f16x4 __attribute__((ext_vector_type(4)));
typedef _Float16 f16x8 __attribute__((ext_vector_type(8)));

#define PS01  ((size_t)8192 * 512)     // L0/L1 partial stride (elems)
#define PS2   ((size_t)8192 * 256)     // L2 partial stride (elems)

__device__ __forceinline__ ushort_t f2bf(float f) {
    __bf16 h = (__bf16)f;  // RNE
    return __builtin_bit_cast(ushort_t, h);
}

// async global->LDS 16B copy; LDS dest must be wave-uniform base + lane*16.
__device__ __forceinline__ void gload_lds16(const void* g, void* lds) {
    __builtin_amdgcn_global_load_lds(
        (const __attribute__((address_space(1))) unsigned int*)(uintptr_t)g,
        (__attribute__((address_space(3))) unsigned int*)(unsigned int)(uintptr_t)lds,
        16, 0, 0);
}

// x -> [gelu, b0..b10] (12 bf16). Direct cardinal cubic B-spline:
// basis_j(x) = b(xs - j), xs=(x+1.75)*4;  b(t), a=|t-2|:
//   a<=1: (4-6a^2+3a^3)/6 ; 1<a<2: (2-a)^3/6 ; else 0.
__device__ __forceinline__ void expand12(float x, ushort_t* o) {
    float x3 = x * x * x;
    float y  = 0.7978845608028654f * (x + 0.044715f * x3);
    float e  = __expf(2.0f * y);
    float th = 1.0f - 2.0f / (e + 1.0f);       // tanh(y)
    o[0] = f2bf(0.5f * x * (1.0f + th));
    float xs = (x + 1.75f) * 4.0f;
#pragma unroll
    for (int j = 0; j < 11; ++j) {
        float t  = xs - (float)j;
        float a  = fabsf(t - 2.0f);
        float p1 = (3.0f * a - 6.0f) * a * a + 4.0f;   // a<=1 branch
        float c  = 2.0f - a;
        float p2 = c * c * c;                          // 1<a<2 branch
        float v  = (a <= 1.0f) ? p1 : fmaxf(p2, 0.0f);
        o[1 + j] = f2bf(v * (1.0f / 6.0f));
    }
}

// pack 32 bf16 (from a statically-offset ushort window) into 4 uint4 chunks
__device__ __forceinline__ void pack32(const ushort_t* s, uint4* o) {
#pragma unroll
    for (int c = 0; c < 4; ++c) {
        o[c].x = (unsigned)s[c * 8 + 0] | ((unsigned)s[c * 8 + 1] << 16);
        o[c].y = (unsigned)s[c * 8 + 2] | ((unsigned)s[c * 8 + 3] << 16);
        o[c].z = (unsigned)s[c * 8 + 4] | ((unsigned)s[c * 8 + 5] << 16);
        o[c].w = (unsigned)s[c * 8 + 6] | ((unsigned)s[c * 8 + 7] << 16);
    }
}

// W[o][i*12+0]=base_w[o][i]; W[o][i*12+1+k]=spline_w[o][i][k].
__device__ __forceinline__ void pack_w_item(
    const float* __restrict__ bw, const float* __restrict__ sw,
    ushort_t* __restrict__ W, int idx)
{
    union { ushort_t us[12]; uint2 v[3]; } pk;
    pk.us[0] = f2bf(bw[idx]);
    const float* s = sw + (size_t)idx * 11;
#pragma unroll
    for (int k = 0; k < 11; ++k) pk.us[1 + k] = f2bf(s[k]);
    uint2* dst = (uint2*)(W + (size_t)idx * 12);
    dst[0] = pk.v[0]; dst[1] = pk.v[1]; dst[2] = pk.v[2];
}

// ---------------------------------------------------------------------------
// Tiled expansion body: item = (b, cg), idx = cg*8192 + b. Reads input cols
// [32cg, 32cg+32) of row b contiguously (X fp32 or sum of 4 fp16 partials),
// writes the 12 whole 64-B A'-lines (kb = 12cg..12cg+11). Lanes = consecutive
// b -> coalesced 4-KB wave spans.
// ---------------------------------------------------------------------------
template <int KB, bool FROMX>
__device__ __forceinline__ void expand_item(
    const float* __restrict__ X, const _Float16* __restrict__ Pp,
    ushort_t* __restrict__ A, int idx)
{
    constexpr int F = KB * 8 / 3;                 // 96->256, 192->512
    const int b   = idx & 8191;
    const int cg  = idx >> 13;                    // 0..F/32-1
    const int row = b & 255;
    const int p   = b >> 8;

    float h[32];
    if (FROMX) {
        const float4* xr = (const float4*)(X + (size_t)b * F + cg * 32);
#pragma unroll
        for (int v = 0; v < 8; ++v) {
            float4 f = xr[v];
            h[4 * v + 0] = f.x; h[4 * v + 1] = f.y;
            h[4 * v + 2] = f.z; h[4 * v + 3] = f.w;
        }
    } else {
#pragma unroll
        for (int u = 0; u < 32; ++u) h[u] = 0.f;
#pragma unroll
        for (int z = 0; z < 4; ++z) {
            const f16x8* pr = (const f16x8*)(Pp + z * PS01 + (size_t)b * F + cg * 32);
#pragma unroll
            for (int v = 0; v < 4; ++v) {
                f16x8 a = pr[v];
#pragma unroll
                for (int e = 0; e < 8; ++e) h[8 * v + e] += (float)a[e];
            }
        }
    }

    const size_t lbase = ((size_t)p * KB + 12 * cg) * 256 + row;
#pragma unroll
    for (int ci8 = 0; ci8 < 4; ++ci8) {
        ushort_t us[96];
#pragma unroll
        for (int u = 0; u < 8; ++u) expand12(h[ci8 * 8 + u], us + 12 * u);
#pragma unroll
        for (int kk = 0; kk < 3; ++kk) {
            uint4 o[4];
            pack32(us + 32 * kk, o);
            uint4* dst = (uint4*)(A + (lbase + (size_t)(3 * ci8 + kk) * 256) * 32);
            dst[0] = o[0]; dst[1] = o[1]; dst[2] = o[2]; dst[3] = o[3];
        }
    }
}

// ---------------------------------------------------------------------------
// prep: blocks [0,512) pack W0, [512,1536) W1, [1536,2048) W2 (block-uniform
// ranges), [2048,2304) expand L0. Replaces 4 dispatches with 1.
// ---------------------------------------------------------------------------
__global__ __launch_bounds__(256) void prep_kernel(
    const float* __restrict__ x,
    const float* __restrict__ bw0, const float* __restrict__ sw0,
    const float* __restrict__ bw1, const float* __restrict__ sw1,
    const float* __restrict__ bw2, const float* __restrict__ sw2,
    ushort_t* __restrict__ W0, ushort_t* __restrict__ W1,
    ushort_t* __restrict__ W2, ushort_t* __restrict__ A)
{
    const int bid = blockIdx.x;
    const int idx = bid * 256 + threadIdx.x;
    if (bid < 512)       pack_w_item(bw0, sw0, W0, idx);
    else if (bid < 1536) pack_w_item(bw1, sw1, W1, idx - 131072);
    else if (bid < 2048) pack_w_item(bw2, sw2, W2, idx - 393216);
    else expand_item<96, true>(x, nullptr, A, idx - 524288);
}

// L1/L2 expand: sum 4 fp16 partials, write A' tiled. 512 blocks x 256.
__global__ __launch_bounds__(256) void expand_kernel(
    const _Float16* __restrict__ P, ushort_t* __restrict__ A)
{
    expand_item<192, false>(nullptr, P, A, blockIdx.x * 256 + threadIdx.x);
}

// ---------------------------------------------------------------------------
// GEMM: C_z[M,N] = A'[M,kslice] @ W[N,kslice]^T (bf16 in, fp16 out).
// m201-style 8-barrier 4-phase schedule on BK=64 K-tiles.
// Tile 256x256, 512 threads = 8 waves (wm=w>>2, wn=w&3), wave tile 128x64,
// acc[8][4]. LDS: 2 buffers x {Ak0|Ak1|Bk0|Bk1} x 16 KB = 128 KB; each
// 16-KB region is a 256x32 subtile, rows = 4 chunks of 16 B, LDS(row,c)
// holds logical chunk c ^ ((row>>1)&3) (verified 0 bank conflicts).
//   A frag: lane holds A[m=l15][k=q*8+j];  C/D: D[m=q*4+r][n=l15].
// Per K-tile t (buf=t&1), 4 phases, each {stage 1 half(t+1); ds_read frags;
// s_barrier; lgkmcnt(0); setprio(1); 16 MFMA; setprio(0); s_barrier}:
//   ph0: stage Ak0 | read A[0-3]ks0 + B[0-3]ks0 | MFMA (mi0-3)x(ni0-3)@ks0
//   ph1: stage Ak1 | read A[4-7]ks0            | MFMA (mi4-7)@ks0
//        + vmcnt(4) before closing barrier  [forces Bk1(t) resident]
//   ph2: stage Bk0 | read A[0-3]ks1 + B[0-3]ks1 | MFMA (mi0-3)@ks1
//   ph3: stage Bk1 | read A[4-7]ks1            | MFMA (mi4-7)@ks1
//        + vmcnt(2) before closing barrier  [Ak0/Ak1/Bk0(t+1) resident,
//          Bk1(t+1) stays in flight -- never drains mid-loop]
// Split-K over blockIdx.z -> C + z*M*N (fp16).
// ---------------------------------------------------------------------------
__global__ __launch_bounds__(512, 2) void gemm_kernel(
    const ushort_t* __restrict__ A,  // tiled [p][KBT][256][32]
    const ushort_t* __restrict__ W,  // N x K row-major
    _Float16* __restrict__ C,        // split-K partials (fp16), z*M*N apart
    int M, int N, int KBT, int tps)  // KBT = K/32; tps = BK64-tiles per split
{
    extern __shared__ __align__(16) ushort_t lds[];   // 2 x 32768 = 128 KB

    const int t   = threadIdx.x;
    const int l   = t & 63;
    const int w   = t >> 6;        // 0..7
    const int wm  = w >> 2;        // 0..1  (M half)
    const int wn  = w & 3;         // 0..3  (N quarter)
    const int l15 = l & 15;
    const int q   = l >> 4;        // 0..3
    const int K   = KBT << 5;
    const int blockN = blockIdx.y * 256;
    const int kt0 = blockIdx.z * tps;
    const int nt  = tps;
    _Float16* Cz = C + (size_t)blockIdx.z * M * N;

    const ushort_t* Apan = A + (size_t)blockIdx.x * KBT * 8192;
    const ushort_t* Wb   = W + (size_t)blockN * K;

    // stage A half ks (16 KB contiguous in A') of tile kt into buffer buf
    auto stage_a = [&](int kt, int ks, int buf) {
        ushort_t* d = lds + buf * 32768 + ks * 8192;
        const ushort_t* s0 = Apan + (size_t)(2 * kt + ks) * 8192;
#pragma unroll
        for (int it = 0; it < 2; ++it) {
            int s = it * 512 + t;
            int row = s >> 2, g = (s & 3) ^ ((row >> 1) & 3);
            gload_lds16(s0 + (row << 5) + (g << 3), d + s * 8);
        }
    };
    // stage B half ks (256 rows x 64 B strided) of tile kt into buffer buf
    auto stage_b = [&](int kt, int ks, int buf) {
        ushort_t* d = lds + buf * 32768 + 16384 + ks * 8192;
#pragma unroll
        for (int it = 0; it < 2; ++it) {
            int s = it * 512 + t;
            int row = s >> 2, g = (s & 3) ^ ((row >> 1) & 3);
            gload_lds16(Wb + ((size_t)row * K + (kt << 6) + (ks << 5) + (g << 3)),
                        d + s * 8);
        }
    };
    auto rdA = [&](int buf, int ks, int mi) -> bf16x8 {
        const ushort_t* r = lds + buf * 32768 + ks * 8192;
        int m = wm * 128 + mi * 16 + l15;
        return *(const bf16x8*)&r[(size_t)((m << 2) + (q ^ ((m >> 1) & 3))) * 8];
    };
    auto rdB = [&](int buf, int ks, int ni) -> bf16x8 {
        const ushort_t* r = lds + buf * 32768 + 16384 + ks * 8192;
        int n = wn * 64 + ni * 16 + l15;
        return *(const bf16x8*)&r[(size_t)((n << 2) + (q ^ ((n >> 1) & 3))) * 8];
    };

    f32x4 acc[8][4];
#pragma unroll
    for (int i = 0; i < 8; ++i)
#pragma unroll
        for (int j = 0; j < 4; ++j) acc[i][j] = (f32x4){0.f, 0.f, 0.f, 0.f};

    auto quad = [&](bf16x8* af4, bf16x8* bf4, int mo) {
#pragma unroll
        for (int mi = 0; mi < 4; ++mi)
#pragma unroll
            for (int ni = 0; ni < 4; ++ni)
                acc[mo + mi][ni] = __builtin_amdgcn_mfma_f32_16x16x32_bf16(
                    af4[mi], bf4[ni], acc[mo + mi][ni], 0, 0, 0);
    };

    // prologue: full tile kt0 into buffer 0 (8 loads), drain, barrier.
    stage_a(kt0, 0, 0); stage_a(kt0, 1, 0);
    stage_b(kt0, 0, 0); stage_b(kt0, 1, 0);
    asm volatile("s_waitcnt vmcnt(0)" ::: "memory");
    __builtin_amdgcn_s_barrier();

    bf16x8 af[4], bf0[4], bf1[4];

    for (int tt = 0; tt < nt; ++tt) {
        const int buf  = tt & 1;
        const int nbuf = buf ^ 1;
        const int kt   = kt0 + tt;
        const bool nx  = (tt + 1 < nt);

        // -------- ph0: (mi0-3 x ni0-3) @ ks0 --------
        if (nx) stage_a(kt + 1, 0, nbuf);
#pragma unroll
        for (int i = 0; i < 4; ++i) bf0[i] = rdB(buf, 0, i);
#pragma unroll
        for (int i = 0; i < 4; ++i) af[i] = rdA(buf, 0, i);
        __builtin_amdgcn_s_barrier();
        asm volatile("s_waitcnt lgkmcnt(0)" ::: "memory");
        __builtin_amdgcn_sched_barrier(0);
        __builtin_amdgcn_s_setprio(1);
        quad(af, bf0, 0);
        __builtin_amdgcn_s_setprio(0);
        __builtin_amdgcn_s_barrier();

        // -------- ph1: (mi4-7) @ ks0 --------
        if (nx) stage_a(kt + 1, 1, nbuf);
#pragma unroll
        for (int i = 0; i < 4; ++i) af[i] = rdA(buf, 0, 4 + i);
        __builtin_amdgcn_s_barrier();
        asm volatile("s_waitcnt lgkmcnt(0)" ::: "memory");
        __builtin_amdgcn_sched_barrier(0);
        __builtin_amdgcn_s_setprio(1);
        quad(af, bf0, 4);
        __builtin_amdgcn_s_setprio(0);
        // gate: Bk1(t) must be resident for ph2's reads. Outstanding here:
        // Bk1(t)[2] + Ak0(t+1)[2] + Ak1(t+1)[2] when nx, else Bk1(t)[2].
        if (nx) asm volatile("s_waitcnt vmcnt(4)" ::: "memory");
        else    asm volatile("s_waitcnt vmcnt(0)" ::: "memory");
        __builtin_amdgcn_s_barrier();

        // -------- ph2: (mi0-3 x ni0-3) @ ks1 --------
        if (nx) stage_b(kt + 1, 0, nbuf);
#pragma unroll
        for (int i = 0; i < 4; ++i) bf1[i] = rdB(buf, 1, i);
#pragma unroll
        for (int i = 0; i < 4; ++i) af[i] = rdA(buf, 1, i);
        __builtin_amdgcn_s_barrier();
        asm volatile("s_waitcnt lgkmcnt(0)" ::: "memory");
        __builtin_amdgcn_sched_barrier(0);
        __builtin_amdgcn_s_setprio(1);
        quad(af, bf1, 0);
        __builtin_amdgcn_s_setprio(0);
        __builtin_amdgcn_s_barrier();

        // -------- ph3: (mi4-7) @ ks1 --------
        if (nx) stage_b(kt + 1, 1, nbuf);
#pragma unroll
        for (int i = 0; i < 4; ++i) af[i] = rdA(buf, 1, 4 + i);
        __builtin_amdgcn_s_barrier();
        asm volatile("s_waitcnt lgkmcnt(0)" ::: "memory");
        __builtin_amdgcn_sched_barrier(0);
        __builtin_amdgcn_s_setprio(1);
        quad(af, bf1, 4);
        __builtin_amdgcn_s_setprio(0);
        // gate: Ak0/Ak1/Bk0(t+1) resident for next ph0/ph1; Bk1(t+1) in
        // flight. Outstanding when nx: 8 -> vmcnt(2).
        if (nx) asm volatile("s_waitcnt vmcnt(2)" ::: "memory");
        __builtin_amdgcn_s_barrier();
    }

    const int blockM = blockIdx.x * 256;
    // epilogue: fp16 stores into this split's partial buffer
#pragma unroll
    for (int ni = 0; ni < 4; ++ni) {
        int n = blockN + wn * 64 + ni * 16 + l15;
#pragma unroll
        for (int mi = 0; mi < 8; ++mi) {
            int mb = blockM + wm * 128 + mi * 16 + q * 4;
#pragma unroll
            for (int r = 0; r < 4; ++r)
                Cz[(size_t)(mb + r) * N + n] = (_Float16)acc[mi][ni][r];
        }
    }
}

// ---------------------------------------------------------------------------
// Final: out = gamma*rsqrt(var+eps)*(sum of 8 fp16 partials - mean) + beta.
// ---------------------------------------------------------------------------
__global__ __launch_bounds__(256) void bn_reduce_kernel(
    const _Float16* __restrict__ Q,
    const float* __restrict__ gamma, const float* __restrict__ beta,
    const float* __restrict__ mean,  const float* __restrict__ var,
    float4* __restrict__ out, int n4)
{
    int i = blockIdx.x * 256 + threadIdx.x;
    if (i >= n4) return;
    float sx = 0.f, sy = 0.f, sz = 0.f, sw = 0.f;
#pragma unroll
    for (int s = 0; s < 8; ++s) {
        f16x4 v = *(const f16x4*)(Q + s * PS2 + 4 * (size_t)i);
        sx += (float)v.x; sy += (float)v.y; sz += (float)v.z; sw += (float)v.w;
    }
    int nb = (i * 4) & 255;
    float4 g  = *(const float4*)(gamma + nb);
    float4 be = *(const float4*)(beta + nb);
    float4 mn = *(const float4*)(mean + nb);
    float4 vr = *(const float4*)(var + nb);
    float4 o;
    o.x = g.x * rsqrtf(vr.x + 1e-5f) * (sx - mn.x) + be.x;
    o.y = g.y * rsqrtf(vr.y + 1e-5f) * (sy - mn.y) + be.y;
    o.z = g.z * rsqrtf(vr.z + 1e-5f) * (sz - mn.z) + be.z;
    o.w = g.w * rsqrtf(vr.w + 1e-5f) * (sw - mn.w) + be.w;
    out[i] = o;
}

// ---------------------------------------------------------------------------
extern "C" void kernel_launch(void* const* d_in, const int* in_sizes, int n_in,
                              void* d_out, int out_size, void* d_ws, size_t ws_size,
                              hipStream_t stream) {
    const float* x     = (const float*)d_in[0];
    const float* bw0   = (const float*)d_in[2];
    const float* sw0   = (const float*)d_in[3];
    const float* bw1   = (const float*)d_in[5];
    const float* sw1   = (const float*)d_in[6];
    const float* bw2   = (const float*)d_in[8];
    const float* sw2   = (const float*)d_in[9];
    const float* gamma = (const float*)d_in[10];
    const float* beta  = (const float*)d_in[11];
    const float* mean  = (const float*)d_in[12];
    const float* var   = (const float*)d_in[13];

    char* ws = (char*)d_ws;
    ushort_t*  Abuf = (ushort_t*)(ws);
    ushort_t*  W0   = (ushort_t*)(ws + 100663296);
    ushort_t*  W1   = (ushort_t*)(ws + 103809024);
    ushort_t*  W2   = (ushort_t*)(ws + 110100480);
    _Float16*  P    = (_Float16*)(ws + 113246208);   // 32 MB fp16 partials
    float*     out  = (float*)d_out;

    const size_t GEMM_LDS = 131072;   // 2 buffers x 64 KB

    // prep: 3 weight packs + expand L0 in one dispatch
    prep_kernel<<<2304, 256, 0, stream>>>(x, bw0, sw0, bw1, sw1, bw2, sw2,
                                          W0, W1, W2, Abuf);
    // layer 0: K=3072 (KBT=96, 48 BK64-tiles), N=512, SK=4 (tps=12)
    {
        dim3 g(32, 2, 4);
        gemm_kernel<<<g, 512, GEMM_LDS, stream>>>(Abuf, W0, P, 8192, 512, 96, 12);
    }
    // layer 1: K=6144 (KBT=192, 96 tiles), N=512, SK=4 (tps=24)
    expand_kernel<<<512, 256, 0, stream>>>(P, Abuf);
    {
        dim3 g(32, 2, 4);
        gemm_kernel<<<g, 512, GEMM_LDS, stream>>>(Abuf, W1, P, 8192, 512, 192, 24);
    }
    // layer 2: K=6144 (KBT=192, 96 tiles), N=256, SK=8 (tps=12)
    expand_kernel<<<512, 256, 0, stream>>>(P, Abuf);
    {
        dim3 g(32, 1, 8);
        gemm_kernel<<<g, 512, GEMM_LDS, stream>>>(Abuf, W2, P, 8192, 256, 192, 12);
    }
    // BN + 8-way split-K reduce -> out
    bn_reduce_kernel<<<2048, 256, 0, stream>>>(
        P, gamma, beta, mean, var, (float4*)out, 8192 * 256 / 4);
}

// Round 10
// 333.171 us; speedup vs baseline: 1.9310x; 1.0561x over previous
//
#include <hip/hip_runtime.h>
#include <hip/hip_bf16.h>
#include <cstdint>

// KAN MLP: 256->512->512->256, B=8192, cubic B-splines (uniform grid h=0.25,
// knots -1.75..1.75, 11 bases), BN at the end.
//
// Round-14: seven schedule topologies all land 59-64 us / ~33% MfmaUtil ->
// schedule axis closed; revert to round-6 core (best: 59.0). New lever from
// counters: WRITE_SIZE 57-72 MB for 32 MB logical fp16 partials (vs round-0
// fp32: exactly 33 MB). Cause: epilogue stores 2 B/lane, 16 lanes = 32 B per
// row = HALF-LINE writes -> write-allocate/RFO amplification (~2x). Fix:
// wave-private LDS-transpose epilogue:
//   - wave dumps acc as fp16 into its private 8-KB LDS region (128 rows x
//     32 cols, 64-B rows, proven 2-bit chunk-XOR swizzle = conflict-free),
//   - reads back full 128-B row segments (ds_read_b128, main-loop pattern),
//   - stores f16x8 = 16 B/lane FULL-LINE writes. Two passes (32 cols each).
//   - wave-synchronous (private region; lgkmcnt(0) between passes), values
//     bit-identical (same RNE conversion).
// GEMM main loop = round-6 verbatim: A' tiled [p][kb][256][32] (contiguous
// 16-KB subtile bursts), 256x256 tile, BK=32, 8 waves 2Mx4N, wave 128x64
// acc[8][4], 4 LDS slots x 32 KB, reg-dbuf frags, stage t+3, counted
// vmcnt(4), raw s_barrier, 0 bank conflicts. Expands/prep/bn unchanged.
// Grids: L0 (32,2,4), L1 (32,2,4), L2 (32,1,8) = 256 blocks = 1 block/CU.
//
// Workspace (146,800,640 bytes):
//   A'  @ 0          : 8192*6144*2 = 100,663,296 (tiled layout, all layers)
//   W0  @ 100663296  : 3,145,728
//   W1  @ 103809024  : 6,291,456
//   W2  @ 110100480  : 3,145,728
//   P   @ 113246208  : fp16 partials, 33,554,432 (L0/L1: 4 x 8MB; L2: 8 x 4MB)

typedef unsigned short ushort_t;
typedef __bf16 bf16x8 __attribute__((ext_vector_type(8)));
typedef float f32x4 __attribute__((ext_vector_type(4)));
typedef _Float16 f16x4 __attribute__((ext_vector_type(4)));
typedef _Float16 f16x8 __attribute__((ext_vector_type(8)));

#define PS01  ((size_t)8192 * 512)     // L0/L1 partial stride (elems)
#define PS2   ((size_t)8192 * 256)     // L2 partial stride (elems)

__device__ __forceinline__ ushort_t f2bf(float f) {
    __bf16 h = (__bf16)f;  // RNE
    return __builtin_bit_cast(ushort_t, h);
}
__device__ __forceinline__ ushort_t f2h(float f) {
    _Float16 h = (_Float16)f;  // RNE
    return __builtin_bit_cast(ushort_t, h);
}

// async global->LDS 16B copy; LDS dest must be wave-uniform base + lane*16.
__device__ __forceinline__ void gload_lds16(const void* g, void* lds) {
    __builtin_amdgcn_global_load_lds(
        (const __attribute__((address_space(1))) unsigned int*)(uintptr_t)g,
        (__attribute__((address_space(3))) unsigned int*)(unsigned int)(uintptr_t)lds,
        16, 0, 0);
}

// x -> [gelu, b0..b10] (12 bf16). Direct cardinal cubic B-spline:
// basis_j(x) = b(xs - j), xs=(x+1.75)*4;  b(t), a=|t-2|:
//   a<=1: (4-6a^2+3a^3)/6 ; 1<a<2: (2-a)^3/6 ; else 0.
__device__ __forceinline__ void expand12(float x, ushort_t* o) {
    float x3 = x * x * x;
    float y  = 0.7978845608028654f * (x + 0.044715f * x3);
    float e  = __expf(2.0f * y);
    float th = 1.0f - 2.0f / (e + 1.0f);       // tanh(y)
    o[0] = f2bf(0.5f * x * (1.0f + th));
    float xs = (x + 1.75f) * 4.0f;
#pragma unroll
    for (int j = 0; j < 11; ++j) {
        float t  = xs - (float)j;
        float a  = fabsf(t - 2.0f);
        float p1 = (3.0f * a - 6.0f) * a * a + 4.0f;   // a<=1 branch
        float c  = 2.0f - a;
        float p2 = c * c * c;                          // 1<a<2 branch
        float v  = (a <= 1.0f) ? p1 : fmaxf(p2, 0.0f);
        o[1 + j] = f2bf(v * (1.0f / 6.0f));
    }
}

// pack 32 bf16 (from a statically-offset ushort window) into 4 uint4 chunks
__device__ __forceinline__ void pack32(const ushort_t* s, uint4* o) {
#pragma unroll
    for (int c = 0; c < 4; ++c) {
        o[c].x = (unsigned)s[c * 8 + 0] | ((unsigned)s[c * 8 + 1] << 16);
        o[c].y = (unsigned)s[c * 8 + 2] | ((unsigned)s[c * 8 + 3] << 16);
        o[c].z = (unsigned)s[c * 8 + 4] | ((unsigned)s[c * 8 + 5] << 16);
        o[c].w = (unsigned)s[c * 8 + 6] | ((unsigned)s[c * 8 + 7] << 16);
    }
}

// W[o][i*12+0]=base_w[o][i]; W[o][i*12+1+k]=spline_w[o][i][k].
__device__ __forceinline__ void pack_w_item(
    const float* __restrict__ bw, const float* __restrict__ sw,
    ushort_t* __restrict__ W, int idx)
{
    union { ushort_t us[12]; uint2 v[3]; } pk;
    pk.us[0] = f2bf(bw[idx]);
    const float* s = sw + (size_t)idx * 11;
#pragma unroll
    for (int k = 0; k < 11; ++k) pk.us[1 + k] = f2bf(s[k]);
    uint2* dst = (uint2*)(W + (size_t)idx * 12);
    dst[0] = pk.v[0]; dst[1] = pk.v[1]; dst[2] = pk.v[2];
}

// ---------------------------------------------------------------------------
// Tiled expansion body: item = (b, cg), idx = cg*8192 + b. Reads input cols
// [32cg, 32cg+32) of row b contiguously (X fp32 or sum of 4 fp16 partials),
// writes the 12 whole 64-B A'-lines (kb = 12cg..12cg+11). Lanes = consecutive
// b -> coalesced 4-KB wave spans.
// ---------------------------------------------------------------------------
template <int KB, bool FROMX>
__device__ __forceinline__ void expand_item(
    const float* __restrict__ X, const _Float16* __restrict__ Pp,
    ushort_t* __restrict__ A, int idx)
{
    constexpr int F = KB * 8 / 3;                 // 96->256, 192->512
    const int b   = idx & 8191;
    const int cg  = idx >> 13;                    // 0..F/32-1
    const int row = b & 255;
    const int p   = b >> 8;

    float h[32];
    if (FROMX) {
        const float4* xr = (const float4*)(X + (size_t)b * F + cg * 32);
#pragma unroll
        for (int v = 0; v < 8; ++v) {
            float4 f = xr[v];
            h[4 * v + 0] = f.x; h[4 * v + 1] = f.y;
            h[4 * v + 2] = f.z; h[4 * v + 3] = f.w;
        }
    } else {
#pragma unroll
        for (int u = 0; u < 32; ++u) h[u] = 0.f;
#pragma unroll
        for (int z = 0; z < 4; ++z) {
            const f16x8* pr = (const f16x8*)(Pp + z * PS01 + (size_t)b * F + cg * 32);
#pragma unroll
            for (int v = 0; v < 4; ++v) {
                f16x8 a = pr[v];
#pragma unroll
                for (int e = 0; e < 8; ++e) h[8 * v + e] += (float)a[e];
            }
        }
    }

    const size_t lbase = ((size_t)p * KB + 12 * cg) * 256 + row;
#pragma unroll
    for (int ci8 = 0; ci8 < 4; ++ci8) {
        ushort_t us[96];
#pragma unroll
        for (int u = 0; u < 8; ++u) expand12(h[ci8 * 8 + u], us + 12 * u);
#pragma unroll
        for (int kk = 0; kk < 3; ++kk) {
            uint4 o[4];
            pack32(us + 32 * kk, o);
            uint4* dst = (uint4*)(A + (lbase + (size_t)(3 * ci8 + kk) * 256) * 32);
            dst[0] = o[0]; dst[1] = o[1]; dst[2] = o[2]; dst[3] = o[3];
        }
    }
}

// ---------------------------------------------------------------------------
// prep: blocks [0,512) pack W0, [512,1536) W1, [1536,2048) W2 (block-uniform
// ranges), [2048,2304) expand L0. Replaces 4 dispatches with 1.
// ---------------------------------------------------------------------------
__global__ __launch_bounds__(256) void prep_kernel(
    const float* __restrict__ x,
    const float* __restrict__ bw0, const float* __restrict__ sw0,
    const float* __restrict__ bw1, const float* __restrict__ sw1,
    const float* __restrict__ bw2, const float* __restrict__ sw2,
    ushort_t* __restrict__ W0, ushort_t* __restrict__ W1,
    ushort_t* __restrict__ W2, ushort_t* __restrict__ A)
{
    const int bid = blockIdx.x;
    const int idx = bid * 256 + threadIdx.x;
    if (bid < 512)       pack_w_item(bw0, sw0, W0, idx);
    else if (bid < 1536) pack_w_item(bw1, sw1, W1, idx - 131072);
    else if (bid < 2048) pack_w_item(bw2, sw2, W2, idx - 393216);
    else expand_item<96, true>(x, nullptr, A, idx - 524288);
}

// L1/L2 expand: sum 4 fp16 partials, write A' tiled. 512 blocks x 256.
__global__ __launch_bounds__(256) void expand_kernel(
    const _Float16* __restrict__ P, ushort_t* __restrict__ A)
{
    expand_item<192, false>(nullptr, P, A, blockIdx.x * 256 + threadIdx.x);
}

// ---------------------------------------------------------------------------
// GEMM: C_z[M,N] = A'[M,kslice] @ W[N,kslice]^T (bf16 in, fp16 out).
// Main loop = round-6 verbatim (59.0 us best-of-seven):
//   A' tiled [p][kb][256][32]: subtile stage = contiguous 16 KB burst.
//   Tile 256x256, BK=32, 512 threads = 8 waves (wm, wn), wave 128x64 ->
//   acc[8][4]. LDS: 4 slots of {A 256x32 | B 256x32}; rows = 4 chunks of
//   16 B, LDS(row,c) holds logical chunk c ^ ((row>>1)&3) (0 conflicts).
//   Pipeline per subtile t: stage(t+3) || ds_read frags(t+1) -> ALT regs ||
//   32 MFMA on CUR regs; lgkmcnt(0); vmcnt(4); s_barrier. Ping-pong via
//   unrolled even/odd bodies.
// NEW epilogue: wave-private LDS transpose -> full-line 16-B/lane fp16
// stores (kills the half-line write-allocate amplification: WRITE_SIZE
// 57->33 MB predicted). Split-K over blockIdx.z -> C + z*M*N (fp16).
// ---------------------------------------------------------------------------
#define SLOTE 16384   // elements per LDS slot (32 KB): A 8192 + B 8192

__global__ __launch_bounds__(512, 2) void gemm_kernel(
    const ushort_t* __restrict__ A,  // tiled [p][KBT][256][32]
    const ushort_t* __restrict__ W,  // N x K row-major
    _Float16* __restrict__ C,        // split-K partials (fp16), z*M*N apart
    int M, int N, int KBT, int scps) // KBT = K/32; scps multiple of 4
{
    extern __shared__ __align__(16) ushort_t lds[];   // 4*SLOTE = 128 KB

    const int t   = threadIdx.x;
    const int l   = t & 63;
    const int w   = t >> 6;        // 0..7
    const int wm  = w >> 2;        // 0..1  (M half)
    const int wn  = w & 3;         // 0..3  (N quarter)
    const int l15 = l & 15;
    const int q   = l >> 4;        // 0..3
    const int K   = KBT << 5;
    const int blockN = blockIdx.y * 256;
    const int kb0 = blockIdx.z * scps;
    const int nt  = scps;
    _Float16* Cz = C + (size_t)blockIdx.z * M * N;

    const ushort_t* Apan = A + (size_t)blockIdx.x * KBT * 8192;
    const ushort_t* Wb   = W + (size_t)blockN * K;

    // stage one 32-k subtile: A = contiguous 16 KB (tiled layout); B = 256
    // rows x 64 B strided. Source chunk XOR'd within each 64-B line so LDS
    // (row,c) holds logical chunk c ^ ((row>>1)&3); dest linear (required).
    auto stage = [&](int kb, int slot) {
        ushort_t* da = lds + slot * SLOTE;
        ushort_t* db = da + 8192;
        const ushort_t* sa = Apan + (size_t)kb * 8192;
#pragma unroll
        for (int it = 0; it < 2; ++it) {
            int s = it * 512 + t;
            int row = s >> 2, g = (s & 3) ^ ((row >> 1) & 3);
            gload_lds16(sa + (row << 5) + (g << 3), da + s * 8);
        }
#pragma unroll
        for (int it = 0; it < 2; ++it) {
            int s = it * 512 + t;
            int row = s >> 2, g = (s & 3) ^ ((row >> 1) & 3);
            gload_lds16(Wb + ((size_t)row * K + (kb << 5) + (g << 3)), db + s * 8);
        }
    };

    // 12 ds_read_b128 of one subtile's fragments into the given reg arrays.
    auto ldfrags = [&](int slot, bf16x8* afr, bf16x8* bfr) {
        const ushort_t* Ac = lds + slot * SLOTE;
        const ushort_t* Bc = Ac + 8192;
#pragma unroll
        for (int ni = 0; ni < 4; ++ni) {
            int n = wn * 64 + ni * 16 + l15;
            bfr[ni] = *(const bf16x8*)&Bc[(size_t)((n << 2) + (q ^ ((n >> 1) & 3))) * 8];
        }
#pragma unroll
        for (int mi = 0; mi < 8; ++mi) {
            int m = wm * 128 + mi * 16 + l15;
            afr[mi] = *(const bf16x8*)&Ac[(size_t)((m << 2) + (q ^ ((m >> 1) & 3))) * 8];
        }
    };

    f32x4 acc[8][4];
#pragma unroll
    for (int i = 0; i < 8; ++i)
#pragma unroll
        for (int j = 0; j < 4; ++j) acc[i][j] = (f32x4){0.f, 0.f, 0.f, 0.f};

    // prologue: stage 0,1,2; ensure 0 AND 1 resident (frags(1) read at tt=0).
    stage(kb0 + 0, 0); stage(kb0 + 1, 1); stage(kb0 + 2, 2);
    asm volatile("s_waitcnt vmcnt(4)" ::: "memory");
    __builtin_amdgcn_s_barrier();

    bf16x8 aA[8], bA[4], aB[8], bB[4];
    ldfrags(0, aA, bA);
    asm volatile("s_waitcnt lgkmcnt(0)" ::: "memory");

    // per-subtile body: compute on (ac,bc)=frags(tt); prefetch frags(tt+1)
    // into (an,bn); stage subtile tt+3.
    auto body = [&](int tt, bf16x8* ac, bf16x8* bc, bf16x8* an, bf16x8* bn) {
        if (tt + 3 < nt) stage(kb0 + tt + 3, (tt + 3) & 3);
        if (tt + 1 < nt) ldfrags((tt + 1) & 3, an, bn);
        __builtin_amdgcn_sched_barrier(0);   // pin loads/reads before MFMAs
        __builtin_amdgcn_s_setprio(1);
#pragma unroll
        for (int mi = 0; mi < 8; ++mi)
#pragma unroll
            for (int ni = 0; ni < 4; ++ni)
                acc[mi][ni] = __builtin_amdgcn_mfma_f32_16x16x32_bf16(
                    ac[mi], bc[ni], acc[mi][ni], 0, 0, 0);
        __builtin_amdgcn_s_setprio(0);
        // alt-frag reads drained under the MFMA shadow -> near-free wait.
        asm volatile("s_waitcnt lgkmcnt(0)" ::: "memory");
        // subtile tt+2 resident for next iter's prefetch; tt+3 in flight.
        if (tt + 3 < nt)      asm volatile("s_waitcnt vmcnt(4)" ::: "memory");
        else if (tt + 2 < nt) asm volatile("s_waitcnt vmcnt(0)" ::: "memory");
        __builtin_amdgcn_s_barrier();
    };

    for (int tt = 0; tt < nt; tt += 2) {
        body(tt,     aA, bA, aB, bB);
        body(tt + 1, aB, bB, aA, bA);
    }

    // ---- epilogue: wave-private LDS transpose -> full-line fp16 stores ----
    // wave w owns lds[w*4096 .. +4096) (8 KB = 128 rows x 32 cols fp16),
    // 64-B rows, chunk-XOR swizzle (2-way max = free, main-loop-proven).
    // Two passes of 32 cols (ni pairs). Wave-synchronous: no barriers.
    __syncthreads();   // all waves done reading the shared main-loop slots
    {
        const int blockM = blockIdx.x * 256;
        ushort_t* slot = lds + w * 4096;
        const int rl = l >> 2;        // 0..15 (row sub-index for read pass)
        const int rc = l & 3;         // 0..3  (chunk for read pass)
#pragma unroll
        for (int h = 0; h < 2; ++h) {
            // write pass: acc (ni = 2h, 2h+1) -> slot
#pragma unroll
            for (int mi = 0; mi < 8; ++mi)
#pragma unroll
                for (int nj = 0; nj < 2; ++nj)
#pragma unroll
                    for (int r = 0; r < 4; ++r) {
                        int row = mi * 16 + q * 4 + r;
                        int col = nj * 16 + l15;              // 0..31
                        int c   = col >> 3;                   // 0..3
                        int ad  = row * 32 + ((c ^ ((row >> 1) & 3)) << 3)
                                + (col & 7);
                        slot[ad] = f2h(acc[mi][2 * h + nj][r]);
                    }
            asm volatile("s_waitcnt lgkmcnt(0)" ::: "memory");
            // read+store pass: full 64-B lines, 16 B/lane
#pragma unroll
            for (int it = 0; it < 8; ++it) {
                int row = it * 16 + rl;
                f16x8 v = *(const f16x8*)&slot[row * 32 +
                              ((rc ^ ((row >> 1) & 3)) << 3)];
                _Float16* dst = Cz + (size_t)(blockM + wm * 128 + row) * N
                              + (blockN + wn * 64 + h * 32 + rc * 8);
                *(f16x8*)dst = v;
            }
            // reads of this pass must finish before pass h+1 overwrites slot
            asm volatile("s_waitcnt lgkmcnt(0)" ::: "memory");
        }
    }
}

// ---------------------------------------------------------------------------
// Final: out = gamma*rsqrt(var+eps)*(sum of 8 fp16 partials - mean) + beta.
// ---------------------------------------------------------------------------
__global__ __launch_bounds__(256) void bn_reduce_kernel(
    const _Float16* __restrict__ Q,
    const float* __restrict__ gamma, const float* __restrict__ beta,
    const float* __restrict__ mean,  const float* __restrict__ var,
    float4* __restrict__ out, int n4)
{
    int i = blockIdx.x * 256 + threadIdx.x;
    if (i >= n4) return;
    float sx = 0.f, sy = 0.f, sz = 0.f, sw = 0.f;
#pragma unroll
    for (int s = 0; s < 8; ++s) {
        f16x4 v = *(const f16x4*)(Q + s * PS2 + 4 * (size_t)i);
        sx += (float)v.x; sy += (float)v.y; sz += (float)v.z; sw += (float)v.w;
    }
    int nb = (i * 4) & 255;
    float4 g  = *(const float4*)(gamma + nb);
    float4 be = *(const float4*)(beta + nb);
    float4 mn = *(const float4*)(mean + nb);
    float4 vr = *(const float4*)(var + nb);
    float4 o;
    o.x = g.x * rsqrtf(vr.x + 1e-5f) * (sx - mn.x) + be.x;
    o.y = g.y * rsqrtf(vr.y + 1e-5f) * (sy - mn.y) + be.y;
    o.z = g.z * rsqrtf(vr.z + 1e-5f) * (sz - mn.z) + be.z;
    o.w = g.w * rsqrtf(vr.w + 1e-5f) * (sw - mn.w) + be.w;
    out[i] = o;
}

// ---------------------------------------------------------------------------
extern "C" void kernel_launch(void* const* d_in, const int* in_sizes, int n_in,
                              void* d_out, int out_size, void* d_ws, size_t ws_size,
                              hipStream_t stream) {
    const float* x     = (const float*)d_in[0];
    const float* bw0   = (const float*)d_in[2];
    const float* sw0   = (const float*)d_in[3];
    const float* bw1   = (const float*)d_in[5];
    const float* sw1   = (const float*)d_in[6];
    const float* bw2   = (const float*)d_in[8];
    const float* sw2   = (const float*)d_in[9];
    const float* gamma = (const float*)d_in[10];
    const float* beta  = (const float*)d_in[11];
    const float* mean  = (const float*)d_in[12];
    const float* var   = (const float*)d_in[13];

    char* ws = (char*)d_ws;
    ushort_t*  Abuf = (ushort_t*)(ws);
    ushort_t*  W0   = (ushort_t*)(ws + 100663296);
    ushort_t*  W1   = (ushort_t*)(ws + 103809024);
    ushort_t*  W2   = (ushort_t*)(ws + 110100480);
    _Float16*  P    = (_Float16*)(ws + 113246208);   // 32 MB fp16 partials
    float*     out  = (float*)d_out;

    const size_t GEMM_LDS = 4 * SLOTE * sizeof(ushort_t);  // 131072 B

    // prep: 3 weight packs + expand L0 in one dispatch
    prep_kernel<<<2304, 256, 0, stream>>>(x, bw0, sw0, bw1, sw1, bw2, sw2,
                                          W0, W1, W2, Abuf);
    // layer 0: K=3072 (KBT=96), N=512, SK=4 (scps=24)
    {
        dim3 g(32, 2, 4);
        gemm_kernel<<<g, 512, GEMM_LDS, stream>>>(Abuf, W0, P, 8192, 512, 96, 24);
    }
    // layer 1: K=6144 (KBT=192), N=512, SK=4 (scps=48)
    expand_kernel<<<512, 256, 0, stream>>>(P, Abuf);
    {
        dim3 g(32, 2, 4);
        gemm_kernel<<<g, 512, GEMM_LDS, stream>>>(Abuf, W1, P, 8192, 512, 192, 48);
    }
    // layer 2: K=6144 (KBT=192), N=256, SK=8 (scps=24)
    expand_kernel<<<512, 256, 0, stream>>>(P, Abuf);
    {
        dim3 g(32, 1, 8);
        gemm_kernel<<<g, 512, GEMM_LDS, stream>>>(Abuf, W2, P, 8192, 256, 192, 24);
    }
    // BN + 8-way split-K reduce -> out
    bn_reduce_kernel<<<2048, 256, 0, stream>>>(
        P, gamma, beta, mean, var, (float4*)out, 8192 * 256 / 4);
}